// Round 7
// baseline (241.321 us; speedup 1.0000x reference)
//
#include <hip/hip_runtime.h>

#define N_NODES 50000
#define N_EDGES 1600000
#define IN_DIM 512
#define HID_DIM 128
#define OUT_DIM 16

#define BKT_SHIFT 6
#define BKT_NODES 64
#define NB ((N_NODES + BKT_NODES - 1) / BKT_NODES)   // 782 buckets

typedef __attribute__((ext_vector_type(8))) __bf16 bf16x8;
typedef __attribute__((ext_vector_type(8))) unsigned short ushort8;
typedef __attribute__((ext_vector_type(4))) float f32x4;

static __device__ __forceinline__ unsigned short f2bf(float x) {
    unsigned int u = __float_as_uint(x);
    u += 0x7FFFu + ((u >> 16) & 1u);   // round-to-nearest-even
    return (unsigned short)(u >> 16);
}
static __device__ __forceinline__ float bf2f(unsigned short v) {
    return __uint_as_float(((unsigned int)v) << 16);
}

__device__ inline int wave_incl_scan(int v) {
    #pragma unroll
    for (int off = 1; off < 64; off <<= 1) {
        int x = __shfl_up(v, off, 64);
        if ((threadIdx.x & 63) >= off) v += x;
    }
    return v;
}

// ================= CSR build =================

// 391 blocks x 4096 edges
__global__ __launch_bounds__(256) void bucket_hist_kernel(const int* __restrict__ dst,
                                                          int* __restrict__ bcnt) {
    __shared__ int lc[NB];
    const int t = threadIdx.x;
    for (int b = t; b < NB; b += 256) lc[b] = 0;
    __syncthreads();
    const int e0 = blockIdx.x * 4096;
    #pragma unroll
    for (int i = 0; i < 16; i++) {
        int e = e0 + i * 256 + t;
        if (e < N_EDGES) atomicAdd(&lc[dst[e] >> BKT_SHIFT], 1);
    }
    __syncthreads();
    for (int b = t; b < NB; b += 256)
        if (lc[b]) atomicAdd(&bcnt[b], lc[b]);
}

__global__ __launch_bounds__(1024) void bucket_scan_kernel(const int* __restrict__ bcnt,
                                                           int* __restrict__ bucket_ptr,
                                                           int* __restrict__ cursor) {
    __shared__ int wsums[16];
    const int t = threadIdx.x;
    const int lane = t & 63, wid = t >> 6;
    int v = (t < NB) ? bcnt[t] : 0;
    int incl = wave_incl_scan(v);
    if (lane == 63) wsums[wid] = incl;
    __syncthreads();
    if (wid == 0) {
        int wv = (lane < 16) ? wsums[lane] : 0;
        int ws = wave_incl_scan(wv);
        if (lane < 16) wsums[lane] = ws;
    }
    __syncthreads();
    int woff = wid ? wsums[wid - 1] : 0;
    int excl = woff + incl - v;
    if (t < NB) { bucket_ptr[t] = excl; cursor[t] = excl; }
    if (t == NB - 1) bucket_ptr[NB] = excl + v;
}

// 391 blocks x 4096 edges. pairs_bkt[i] = {src | (dstlocal<<16), val}, bucket-ordered
__global__ __launch_bounds__(256) void bucket_scatter_kernel(const int* __restrict__ src,
                                                             const int* __restrict__ dst,
                                                             const float* __restrict__ val,
                                                             int* __restrict__ cursor,
                                                             int2* __restrict__ pairs_bkt) {
    __shared__ int cnt[NB];
    __shared__ int bbase[NB];
    const int t = threadIdx.x;
    const int e0 = blockIdx.x * 4096;
    for (int b = t; b < NB; b += 256) cnt[b] = 0;
    __syncthreads();
    #pragma unroll
    for (int i = 0; i < 16; i++) {
        int e = e0 + i * 256 + t;
        if (e < N_EDGES) atomicAdd(&cnt[dst[e] >> BKT_SHIFT], 1);
    }
    __syncthreads();
    for (int b = t; b < NB; b += 256) {
        int c = cnt[b];
        bbase[b] = c ? atomicAdd(&cursor[b], c) : 0;
        cnt[b] = 0;
    }
    __syncthreads();
    #pragma unroll
    for (int i = 0; i < 16; i++) {
        int e = e0 + i * 256 + t;
        if (e < N_EDGES) {
            int dd = dst[e];
            int b = dd >> BKT_SHIFT, dl = dd & (BKT_NODES - 1);
            int pos = bbase[b] + atomicAdd(&cnt[b], 1);
            int2 pr;
            pr.x = src[e] | (dl << 16);
            pr.y = __float_as_int(val[e]);
            pairs_bkt[pos] = pr;
        }
    }
}

// Fused node-level CSR: per bucket, hist by dst-local -> scan -> row_ptr -> permute.
__global__ __launch_bounds__(256) void node_sort_fused_kernel(const int2* __restrict__ pairs_bkt,
                                                              const int* __restrict__ bucket_ptr,
                                                              int* __restrict__ row_ptr,
                                                              int2* __restrict__ pairs) {
    __shared__ int cnt[BKT_NODES];
    __shared__ int base[BKT_NODES];
    const int t = threadIdx.x;
    const int b = blockIdx.x;
    const int s = bucket_ptr[b], e = bucket_ptr[b + 1];
    if (t < BKT_NODES) cnt[t] = 0;
    __syncthreads();
    for (int i = s + t; i < e; i += 256)
        atomicAdd(&cnt[pairs_bkt[i].x >> 16], 1);
    __syncthreads();
    if (t < BKT_NODES) {
        int v = cnt[t];
        int incl = wave_incl_scan(v);       // wave 0, 64 lanes
        base[t] = s + incl - v;
    }
    __syncthreads();
    if (t < BKT_NODES) {
        int n = b * BKT_NODES + t;
        if (n < N_NODES) row_ptr[n] = base[t];
        cnt[t] = 0;
    }
    if (b == NB - 1 && t == 0) row_ptr[N_NODES] = N_EDGES;
    __syncthreads();
    for (int i = s + t; i < e; i += 256) {
        int2 pr = pairs_bkt[i];
        int dl = pr.x >> 16;
        int p = base[dl] + atomicAdd(&cnt[dl], 1);
        pairs[p] = pr;
    }
}

// ================= compute =================

__global__ void prep_w1_kernel(const float* __restrict__ W1, unsigned short* __restrict__ Wt) {
    int i = blockIdx.x * 256 + threadIdx.x;
    if (i < IN_DIM * HID_DIM) {
        int k = i >> 7, col = i & 127;
        Wt[(size_t)col * IN_DIM + k] = f2bf(W1[i]);
    }
}

// GEMM1 (bf16 MFMA, zero-LDS): h0 = bf16(X @ W1)
// 512 thr = 8 waves (2M x 4N); wave tile 32x32 = 2x2 of 16x16x32. BM=64 -> 782 blocks.
__global__ __launch_bounds__(512) void gemm1_kernel(const float* __restrict__ X,
                                                    const unsigned short* __restrict__ Wt,
                                                    unsigned short* __restrict__ h0) {
    const int t = threadIdx.x;
    const int lane = t & 63;
    const int wave = t >> 6;
    const int wr = wave >> 2, wc = wave & 3;
    const int c = lane & 15, g = lane >> 4;
    const int m0 = blockIdx.x * 64 + wr * 32;

    f32x4 acc[2][2];
    #pragma unroll
    for (int mt = 0; mt < 2; mt++)
        #pragma unroll
        for (int nt = 0; nt < 2; nt++) acc[mt][nt] = (f32x4){0.f, 0.f, 0.f, 0.f};

    const float* aptr[2];
    #pragma unroll
    for (int mt = 0; mt < 2; mt++) {
        int r = m0 + mt * 16 + c;
        r = (r < N_NODES) ? r : (N_NODES - 1);
        aptr[mt] = X + (size_t)r * IN_DIM + g * 8;
    }
    const unsigned short* bptr[2];
    #pragma unroll
    for (int nt = 0; nt < 2; nt++) {
        int col = wc * 32 + nt * 16 + c;
        bptr[nt] = Wt + (size_t)col * IN_DIM + g * 8;
    }

    for (int k0 = 0; k0 < IN_DIM; k0 += 32) {
        bf16x8 bfrag[2];
        #pragma unroll
        for (int nt = 0; nt < 2; nt++)
            bfrag[nt] = *(const bf16x8*)(bptr[nt] + k0);
        #pragma unroll
        for (int mt = 0; mt < 2; mt++) {
            float4 a0 = *(const float4*)(aptr[mt] + k0);
            float4 a1 = *(const float4*)(aptr[mt] + k0 + 4);
            ushort8 af;
            af[0] = f2bf(a0.x); af[1] = f2bf(a0.y); af[2] = f2bf(a0.z); af[3] = f2bf(a0.w);
            af[4] = f2bf(a1.x); af[5] = f2bf(a1.y); af[6] = f2bf(a1.z); af[7] = f2bf(a1.w);
            bf16x8 afrag = __builtin_bit_cast(bf16x8, af);
            #pragma unroll
            for (int nt = 0; nt < 2; nt++)
                acc[mt][nt] = __builtin_amdgcn_mfma_f32_16x16x32_bf16(afrag, bfrag[nt],
                                                                      acc[mt][nt], 0, 0, 0);
        }
    }

    #pragma unroll
    for (int mt = 0; mt < 2; mt++) {
        #pragma unroll
        for (int r = 0; r < 4; r++) {
            int row = m0 + mt * 16 + g * 4 + r;
            if (row < N_NODES) {
                #pragma unroll
                for (int nt = 0; nt < 2; nt++) {
                    int col = wc * 32 + nt * 16 + c;
                    h0[(size_t)row * HID_DIM + col] = f2bf(acc[mt][nt][r]);
                }
            }
        }
    }
}

// SpMM1 + ReLU: one wave per dst node (wave-uniform n -> scalar pair loads).
__global__ __launch_bounds__(256) void spmm1_node_kernel(const unsigned short* __restrict__ h0,
                                                         const int* __restrict__ row_ptr,
                                                         const int2* __restrict__ pairs,
                                                         float* __restrict__ h) {
    const int wid = __builtin_amdgcn_readfirstlane(threadIdx.x >> 6);
    const int n = blockIdx.x * 4 + wid;            // wave-uniform, max 49999
    const int lane = threadIdx.x & 63;
    const int s = row_ptr[n], e = row_ptr[n + 1];  // scalar loads
    float ax = 0.f, ay = 0.f;
    int i = s;
    for (; i + 4 <= e; i += 4) {
        int2 p0 = pairs[i], p1 = pairs[i + 1], p2 = pairs[i + 2], p3 = pairs[i + 3];
        const unsigned short* r0 = h0 + (size_t)(p0.x & 0xFFFF) * HID_DIM;
        const unsigned short* r1 = h0 + (size_t)(p1.x & 0xFFFF) * HID_DIM;
        const unsigned short* r2 = h0 + (size_t)(p2.x & 0xFFFF) * HID_DIM;
        const unsigned short* r3 = h0 + (size_t)(p3.x & 0xFFFF) * HID_DIM;
        unsigned int g0 = *(const unsigned int*)(r0 + lane * 2);
        unsigned int g1 = *(const unsigned int*)(r1 + lane * 2);
        unsigned int g2 = *(const unsigned int*)(r2 + lane * 2);
        unsigned int g3 = *(const unsigned int*)(r3 + lane * 2);
        float v0 = __int_as_float(p0.y), v1 = __int_as_float(p1.y);
        float v2 = __int_as_float(p2.y), v3 = __int_as_float(p3.y);
        ax += v0 * bf2f((unsigned short)g0) + v1 * bf2f((unsigned short)g1)
            + v2 * bf2f((unsigned short)g2) + v3 * bf2f((unsigned short)g3);
        ay += v0 * bf2f((unsigned short)(g0 >> 16)) + v1 * bf2f((unsigned short)(g1 >> 16))
            + v2 * bf2f((unsigned short)(g2 >> 16)) + v3 * bf2f((unsigned short)(g3 >> 16));
    }
    for (; i < e; i++) {
        int2 pr = pairs[i];
        const unsigned short* r0 = h0 + (size_t)(pr.x & 0xFFFF) * HID_DIM;
        unsigned int gv = *(const unsigned int*)(r0 + lane * 2);
        float v = __int_as_float(pr.y);
        ax += v * bf2f((unsigned short)gv);
        ay += v * bf2f((unsigned short)(gv >> 16));
    }
    float2 r = make_float2(fmaxf(ax, 0.f), fmaxf(ay, 0.f));
    *(float2*)&h[(size_t)n * HID_DIM + lane * 2] = r;
}

// GEMM2: h2[N,16] = h[N,128] @ W2[128,16]
__global__ __launch_bounds__(256) void gemm2_kernel(const float* __restrict__ H,
                                                    const float* __restrict__ W2,
                                                    float* __restrict__ C) {
    __shared__ float Hs[16][132];
    __shared__ float Ws[128][16];
    const int t = threadIdx.x;
    const int n0 = blockIdx.x * 16;
    #pragma unroll
    for (int p = 0; p < 2; p++) {
        int idx = p * 256 + t;
        ((float4*)Ws)[idx] = ((const float4*)W2)[idx];
    }
    #pragma unroll
    for (int p = 0; p < 2; p++) {
        int idx = p * 256 + t;
        int row = idx >> 5, col = (idx & 31) * 4;
        int gr = n0 + row;
        float4 v = make_float4(0.f, 0.f, 0.f, 0.f);
        if (gr < N_NODES) v = *(const float4*)&H[(size_t)gr * HID_DIM + col];
        Hs[row][col + 0] = v.x; Hs[row][col + 1] = v.y;
        Hs[row][col + 2] = v.z; Hs[row][col + 3] = v.w;
    }
    __syncthreads();
    const int nl = t >> 4, j = t & 15;
    float acc = 0.f;
    #pragma unroll 8
    for (int k = 0; k < 128; k++) acc += Hs[nl][k] * Ws[k][j];
    int n = n0 + nl;
    if (n < N_NODES) C[(size_t)n * OUT_DIM + j] = acc;
}

// SpMM2: quarter-wave (16 lanes) per dst node.
__global__ __launch_bounds__(256) void spmm2_node_kernel(const float* __restrict__ h2,
                                                         const int* __restrict__ row_ptr,
                                                         const int2* __restrict__ pairs,
                                                         float* __restrict__ out) {
    const int idx = blockIdx.x * 256 + threadIdx.x;
    const int n = idx >> 4;
    const int d = idx & 15;
    if (n >= N_NODES) return;
    const int s = row_ptr[n], e = row_ptr[n + 1];
    float acc = 0.f;
    int i = s;
    for (; i + 4 <= e; i += 4) {
        int2 p0 = pairs[i], p1 = pairs[i + 1], p2 = pairs[i + 2], p3 = pairs[i + 3];
        float g0 = h2[(size_t)(p0.x & 0xFFFF) * OUT_DIM + d];
        float g1 = h2[(size_t)(p1.x & 0xFFFF) * OUT_DIM + d];
        float g2 = h2[(size_t)(p2.x & 0xFFFF) * OUT_DIM + d];
        float g3 = h2[(size_t)(p3.x & 0xFFFF) * OUT_DIM + d];
        acc += __int_as_float(p0.y) * g0 + __int_as_float(p1.y) * g1
             + __int_as_float(p2.y) * g2 + __int_as_float(p3.y) * g3;
    }
    for (; i < e; i++) {
        int2 pr = pairs[i];
        acc += __int_as_float(pr.y) * h2[(size_t)(pr.x & 0xFFFF) * OUT_DIM + d];
    }
    out[(size_t)n * OUT_DIM + d] = acc;
}

// ================= launch =================

extern "C" void kernel_launch(void* const* d_in, const int* in_sizes, int n_in,
                              void* d_out, int out_size, void* d_ws, size_t ws_size,
                              hipStream_t stream) {
    const float* feature   = (const float*)d_in[0];
    const int*   edge_src  = (const int*)d_in[1];
    const int*   edge_dst  = (const int*)d_in[2];
    const float* edge_vals = (const float*)d_in[3];
    const float* W1        = (const float*)d_in[4];
    const float* W2        = (const float*)d_in[5];
    float* out = (float*)d_out;

    char* ws = (char*)d_ws;
    size_t off = 0;
    auto alloc = [&](size_t bytes) {
        void* p = ws + off;
        off += (bytes + 255) & ~(size_t)255;
        return p;
    };
    unsigned short* h0    = (unsigned short*)alloc((size_t)N_NODES * HID_DIM * 2);
    unsigned short* Wt    = (unsigned short*)alloc((size_t)IN_DIM * HID_DIM * 2);
    float* h              = (float*)alloc((size_t)N_NODES * HID_DIM * 4);
    float* h2             = (float*)alloc((size_t)N_NODES * OUT_DIM * 4);
    int*   bcnt           = (int*)alloc((size_t)NB * 4);
    int*   bucket_ptr     = (int*)alloc((size_t)(NB + 1) * 4);
    int*   cursor         = (int*)alloc((size_t)NB * 4);
    int*   row_ptr        = (int*)alloc((size_t)(N_NODES + 1) * 4);
    int2*  pairs_bkt      = (int2*)alloc((size_t)N_EDGES * 8);
    int2*  pairs          = (int2*)alloc((size_t)N_EDGES * 8);

    hipMemsetAsync(bcnt, 0, (size_t)NB * 4, stream);

    bucket_hist_kernel<<<(N_EDGES + 4095) / 4096, 256, 0, stream>>>(edge_dst, bcnt);
    bucket_scan_kernel<<<1, 1024, 0, stream>>>(bcnt, bucket_ptr, cursor);
    bucket_scatter_kernel<<<(N_EDGES + 4095) / 4096, 256, 0, stream>>>(edge_src, edge_dst,
                                                                       edge_vals, cursor,
                                                                       pairs_bkt);
    node_sort_fused_kernel<<<NB, 256, 0, stream>>>(pairs_bkt, bucket_ptr, row_ptr, pairs);

    prep_w1_kernel<<<(IN_DIM * HID_DIM + 255) / 256, 256, 0, stream>>>(W1, Wt);
    gemm1_kernel<<<(N_NODES + 63) / 64, 512, 0, stream>>>(feature, Wt, h0);
    spmm1_node_kernel<<<(N_NODES + 3) / 4, 256, 0, stream>>>(h0, row_ptr, pairs, h);
    gemm2_kernel<<<(N_NODES + 15) / 16, 256, 0, stream>>>(h, W2, h2);
    spmm2_node_kernel<<<(N_NODES * 16 + 255) / 256, 256, 0, stream>>>(h2, row_ptr, pairs, out);
}

// Round 8
// 178.651 us; speedup vs baseline: 1.3508x; 1.3508x over previous
//
#include <hip/hip_runtime.h>

#define N_NODES 50000
#define N_EDGES 1600000
#define IN_DIM 512
#define HID_DIM 128
#define OUT_DIM 16

#define BKT_SHIFT 6
#define BKT_NODES 64
#define NB ((N_NODES + BKT_NODES - 1) / BKT_NODES)   // 782 buckets

typedef __attribute__((ext_vector_type(8))) __bf16 bf16x8;
typedef __attribute__((ext_vector_type(8))) unsigned short ushort8;
typedef __attribute__((ext_vector_type(4))) unsigned short ushort4v;
typedef __attribute__((ext_vector_type(4))) float f32x4;

static __device__ __forceinline__ unsigned short f2bf(float x) {
    unsigned int u = __float_as_uint(x);
    u += 0x7FFFu + ((u >> 16) & 1u);   // round-to-nearest-even
    return (unsigned short)(u >> 16);
}
static __device__ __forceinline__ float bf2f(unsigned short v) {
    return __uint_as_float(((unsigned int)v) << 16);
}

__device__ inline int wave_incl_scan(int v) {
    #pragma unroll
    for (int off = 1; off < 64; off <<= 1) {
        int x = __shfl_up(v, off, 64);
        if ((threadIdx.x & 63) >= off) v += x;
    }
    return v;
}

// ================= CSR build =================

// 391 blocks x 4096 edges
__global__ __launch_bounds__(256) void bucket_hist_kernel(const int* __restrict__ dst,
                                                          int* __restrict__ bcnt) {
    __shared__ int lc[NB];
    const int t = threadIdx.x;
    for (int b = t; b < NB; b += 256) lc[b] = 0;
    __syncthreads();
    const int e0 = blockIdx.x * 4096;
    #pragma unroll
    for (int i = 0; i < 16; i++) {
        int e = e0 + i * 256 + t;
        if (e < N_EDGES) atomicAdd(&lc[dst[e] >> BKT_SHIFT], 1);
    }
    __syncthreads();
    for (int b = t; b < NB; b += 256)
        if (lc[b]) atomicAdd(&bcnt[b], lc[b]);
}

__global__ __launch_bounds__(1024) void bucket_scan_kernel(const int* __restrict__ bcnt,
                                                           int* __restrict__ bucket_ptr,
                                                           int* __restrict__ cursor) {
    __shared__ int wsums[16];
    const int t = threadIdx.x;
    const int lane = t & 63, wid = t >> 6;
    int v = (t < NB) ? bcnt[t] : 0;
    int incl = wave_incl_scan(v);
    if (lane == 63) wsums[wid] = incl;
    __syncthreads();
    if (wid == 0) {
        int wv = (lane < 16) ? wsums[lane] : 0;
        int ws = wave_incl_scan(wv);
        if (lane < 16) wsums[lane] = ws;
    }
    __syncthreads();
    int woff = wid ? wsums[wid - 1] : 0;
    int excl = woff + incl - v;
    if (t < NB) { bucket_ptr[t] = excl; cursor[t] = excl; }
    if (t == NB - 1) bucket_ptr[NB] = excl + v;
}

// 391 blocks x 4096 edges. pairs_bkt[i] = {src | (dstlocal<<16), val}, bucket-ordered
__global__ __launch_bounds__(256) void bucket_scatter_kernel(const int* __restrict__ src,
                                                             const int* __restrict__ dst,
                                                             const float* __restrict__ val,
                                                             int* __restrict__ cursor,
                                                             int2* __restrict__ pairs_bkt) {
    __shared__ int cnt[NB];
    __shared__ int bbase[NB];
    const int t = threadIdx.x;
    const int e0 = blockIdx.x * 4096;
    for (int b = t; b < NB; b += 256) cnt[b] = 0;
    __syncthreads();
    #pragma unroll
    for (int i = 0; i < 16; i++) {
        int e = e0 + i * 256 + t;
        if (e < N_EDGES) atomicAdd(&cnt[dst[e] >> BKT_SHIFT], 1);
    }
    __syncthreads();
    for (int b = t; b < NB; b += 256) {
        int c = cnt[b];
        bbase[b] = c ? atomicAdd(&cursor[b], c) : 0;
        cnt[b] = 0;
    }
    __syncthreads();
    #pragma unroll
    for (int i = 0; i < 16; i++) {
        int e = e0 + i * 256 + t;
        if (e < N_EDGES) {
            int dd = dst[e];
            int b = dd >> BKT_SHIFT, dl = dd & (BKT_NODES - 1);
            int pos = bbase[b] + atomicAdd(&cnt[b], 1);
            int2 pr;
            pr.x = src[e] | (dl << 16);
            pr.y = __float_as_int(val[e]);
            pairs_bkt[pos] = pr;
        }
    }
}

// Fused node-level CSR: per bucket, hist by dst-local -> scan -> row_ptr -> permute.
__global__ __launch_bounds__(256) void node_sort_fused_kernel(const int2* __restrict__ pairs_bkt,
                                                              const int* __restrict__ bucket_ptr,
                                                              int* __restrict__ row_ptr,
                                                              int2* __restrict__ pairs) {
    __shared__ int cnt[BKT_NODES];
    __shared__ int base[BKT_NODES];
    const int t = threadIdx.x;
    const int b = blockIdx.x;
    const int s = bucket_ptr[b], e = bucket_ptr[b + 1];
    if (t < BKT_NODES) cnt[t] = 0;
    __syncthreads();
    for (int i = s + t; i < e; i += 256)
        atomicAdd(&cnt[pairs_bkt[i].x >> 16], 1);
    __syncthreads();
    if (t < BKT_NODES) {
        int v = cnt[t];
        int incl = wave_incl_scan(v);       // wave 0, 64 lanes
        base[t] = s + incl - v;
    }
    __syncthreads();
    if (t < BKT_NODES) {
        int n = b * BKT_NODES + t;
        if (n < N_NODES) row_ptr[n] = base[t];
        cnt[t] = 0;
    }
    if (b == NB - 1 && t == 0) row_ptr[N_NODES] = N_EDGES;
    __syncthreads();
    for (int i = s + t; i < e; i += 256) {
        int2 pr = pairs_bkt[i];
        int dl = pr.x >> 16;
        int p = base[dl] + atomicAdd(&cnt[dl], 1);
        pairs[p] = pr;
    }
}

// ================= compute =================

__global__ void prep_w1_kernel(const float* __restrict__ W1, unsigned short* __restrict__ Wt) {
    int i = blockIdx.x * 256 + threadIdx.x;
    if (i < IN_DIM * HID_DIM) {
        int k = i >> 7, col = i & 127;
        Wt[(size_t)col * IN_DIM + k] = f2bf(W1[i]);
    }
}

// GEMM1 (bf16 MFMA, LDS-staged): h0 = bf16(X @ W1)
// BM=64, BN=128, BK=64. 256 thr = 4 waves, each wave: 64(M)x32(N) tile = 4x2 of 16x16x32.
// X staged f32->bf16 coalesced; Wt staged coalesced. LDS row stride 72 shorts (144B):
// quarter-wave frag reads land on distinct even base-banks (~2-way max, free).
#define G1_XSTR 72
#define G1_BSTR 72
__global__ __launch_bounds__(256) void gemm1_kernel(const float* __restrict__ X,
                                                    const unsigned short* __restrict__ Wt,
                                                    unsigned short* __restrict__ h0) {
    __shared__ __align__(16) unsigned short Xs[64 * G1_XSTR];    // 9216 B
    __shared__ __align__(16) unsigned short Bs[128 * G1_BSTR];   // 18432 B
    const int t = threadIdx.x;
    const int lane = t & 63;
    const int wave = t >> 6;           // col group: cols wave*32 .. +31
    const int c = lane & 15, g = lane >> 4;
    const int m0 = blockIdx.x * 64;

    f32x4 acc[4][2];
    #pragma unroll
    for (int mt = 0; mt < 4; mt++)
        #pragma unroll
        for (int nt = 0; nt < 2; nt++) acc[mt][nt] = (f32x4){0.f, 0.f, 0.f, 0.f};

    float4 xr[4];
    ushort8 br[4];

    // stage-load: X tile 64x64 f32 (1024 float4), B tile 128x64 bf16 (1024 ushort8)
    #define G1_LOAD(kt)                                                                  \
        _Pragma("unroll")                                                                \
        for (int p = 0; p < 4; p++) {                                                    \
            int idx = p * 256 + t;                                                       \
            int xrow = idx >> 4, xseg = idx & 15;                                        \
            int grow = m0 + xrow; grow = (grow < N_NODES) ? grow : (N_NODES - 1);        \
            xr[p] = *(const float4*)&X[(size_t)grow * IN_DIM + (kt) * 64 + xseg * 4];    \
            int bcol = idx >> 3, bseg = idx & 7;                                         \
            br[p] = *(const ushort8*)&Wt[(size_t)bcol * IN_DIM + (kt) * 64 + bseg * 8];  \
        }

    G1_LOAD(0)
    for (int kt = 0; kt < 8; kt++) {
        // write staged regs to LDS
        #pragma unroll
        for (int p = 0; p < 4; p++) {
            int idx = p * 256 + t;
            int xrow = idx >> 4, xseg = idx & 15;
            ushort4v xw;
            xw[0] = f2bf(xr[p].x); xw[1] = f2bf(xr[p].y);
            xw[2] = f2bf(xr[p].z); xw[3] = f2bf(xr[p].w);
            *(ushort4v*)&Xs[xrow * G1_XSTR + xseg * 4] = xw;
            int bcol = idx >> 3, bseg = idx & 7;
            *(ushort8*)&Bs[bcol * G1_BSTR + bseg * 8] = br[p];
        }
        __syncthreads();
        if (kt < 7) G1_LOAD(kt + 1)        // prefetch next tile (hidden under MFMA)
        #pragma unroll
        for (int ks = 0; ks < 2; ks++) {
            bf16x8 bf[2];
            #pragma unroll
            for (int nt = 0; nt < 2; nt++) {
                int col = wave * 32 + nt * 16 + c;
                bf[nt] = *(const bf16x8*)&Bs[col * G1_BSTR + ks * 32 + g * 8];
            }
            #pragma unroll
            for (int mt = 0; mt < 4; mt++) {
                bf16x8 af = *(const bf16x8*)&Xs[(mt * 16 + c) * G1_XSTR + ks * 32 + g * 8];
                #pragma unroll
                for (int nt = 0; nt < 2; nt++)
                    acc[mt][nt] = __builtin_amdgcn_mfma_f32_16x16x32_bf16(af, bf[nt],
                                                                          acc[mt][nt], 0, 0, 0);
            }
        }
        __syncthreads();
    }
    #undef G1_LOAD

    // C/D layout: col = lane&15, row_in_tile = (lane>>4)*4 + reg
    #pragma unroll
    for (int mt = 0; mt < 4; mt++) {
        #pragma unroll
        for (int r = 0; r < 4; r++) {
            int row = m0 + mt * 16 + g * 4 + r;
            if (row < N_NODES) {
                #pragma unroll
                for (int nt = 0; nt < 2; nt++) {
                    int col = wave * 32 + nt * 16 + c;
                    h0[(size_t)row * HID_DIM + col] = f2bf(acc[mt][nt][r]);
                }
            }
        }
    }
}

// SpMM1 + ReLU: one wave per dst node (wave-uniform n -> scalar pair loads).
__global__ __launch_bounds__(256) void spmm1_node_kernel(const unsigned short* __restrict__ h0,
                                                         const int* __restrict__ row_ptr,
                                                         const int2* __restrict__ pairs,
                                                         float* __restrict__ h) {
    const int wid = __builtin_amdgcn_readfirstlane(threadIdx.x >> 6);
    const int n = blockIdx.x * 4 + wid;            // wave-uniform, max 49999
    const int lane = threadIdx.x & 63;
    const int s = row_ptr[n], e = row_ptr[n + 1];  // scalar loads
    float ax = 0.f, ay = 0.f;
    int i = s;
    for (; i + 4 <= e; i += 4) {
        int2 p0 = pairs[i], p1 = pairs[i + 1], p2 = pairs[i + 2], p3 = pairs[i + 3];
        const unsigned short* r0 = h0 + (size_t)(p0.x & 0xFFFF) * HID_DIM;
        const unsigned short* r1 = h0 + (size_t)(p1.x & 0xFFFF) * HID_DIM;
        const unsigned short* r2 = h0 + (size_t)(p2.x & 0xFFFF) * HID_DIM;
        const unsigned short* r3 = h0 + (size_t)(p3.x & 0xFFFF) * HID_DIM;
        unsigned int g0 = *(const unsigned int*)(r0 + lane * 2);
        unsigned int g1 = *(const unsigned int*)(r1 + lane * 2);
        unsigned int g2 = *(const unsigned int*)(r2 + lane * 2);
        unsigned int g3 = *(const unsigned int*)(r3 + lane * 2);
        float v0 = __int_as_float(p0.y), v1 = __int_as_float(p1.y);
        float v2 = __int_as_float(p2.y), v3 = __int_as_float(p3.y);
        ax += v0 * bf2f((unsigned short)g0) + v1 * bf2f((unsigned short)g1)
            + v2 * bf2f((unsigned short)g2) + v3 * bf2f((unsigned short)g3);
        ay += v0 * bf2f((unsigned short)(g0 >> 16)) + v1 * bf2f((unsigned short)(g1 >> 16))
            + v2 * bf2f((unsigned short)(g2 >> 16)) + v3 * bf2f((unsigned short)(g3 >> 16));
    }
    for (; i < e; i++) {
        int2 pr = pairs[i];
        const unsigned short* r0 = h0 + (size_t)(pr.x & 0xFFFF) * HID_DIM;
        unsigned int gv = *(const unsigned int*)(r0 + lane * 2);
        float v = __int_as_float(pr.y);
        ax += v * bf2f((unsigned short)gv);
        ay += v * bf2f((unsigned short)(gv >> 16));
    }
    float2 r = make_float2(fmaxf(ax, 0.f), fmaxf(ay, 0.f));
    *(float2*)&h[(size_t)n * HID_DIM + lane * 2] = r;
}

// GEMM2: h2[N,16] = h[N,128] @ W2[128,16]
__global__ __launch_bounds__(256) void gemm2_kernel(const float* __restrict__ H,
                                                    const float* __restrict__ W2,
                                                    float* __restrict__ C) {
    __shared__ float Hs[16][132];
    __shared__ float Ws[128][16];
    const int t = threadIdx.x;
    const int n0 = blockIdx.x * 16;
    #pragma unroll
    for (int p = 0; p < 2; p++) {
        int idx = p * 256 + t;
        ((float4*)Ws)[idx] = ((const float4*)W2)[idx];
    }
    #pragma unroll
    for (int p = 0; p < 2; p++) {
        int idx = p * 256 + t;
        int row = idx >> 5, col = (idx & 31) * 4;
        int gr = n0 + row;
        float4 v = make_float4(0.f, 0.f, 0.f, 0.f);
        if (gr < N_NODES) v = *(const float4*)&H[(size_t)gr * HID_DIM + col];
        Hs[row][col + 0] = v.x; Hs[row][col + 1] = v.y;
        Hs[row][col + 2] = v.z; Hs[row][col + 3] = v.w;
    }
    __syncthreads();
    const int nl = t >> 4, j = t & 15;
    float acc = 0.f;
    #pragma unroll 8
    for (int k = 0; k < 128; k++) acc += Hs[nl][k] * Ws[k][j];
    int n = n0 + nl;
    if (n < N_NODES) C[(size_t)n * OUT_DIM + j] = acc;
}

// SpMM2: quarter-wave (16 lanes) per dst node.
__global__ __launch_bounds__(256) void spmm2_node_kernel(const float* __restrict__ h2,
                                                         const int* __restrict__ row_ptr,
                                                         const int2* __restrict__ pairs,
                                                         float* __restrict__ out) {
    const int idx = blockIdx.x * 256 + threadIdx.x;
    const int n = idx >> 4;
    const int d = idx & 15;
    if (n >= N_NODES) return;
    const int s = row_ptr[n], e = row_ptr[n + 1];
    float acc = 0.f;
    int i = s;
    for (; i + 4 <= e; i += 4) {
        int2 p0 = pairs[i], p1 = pairs[i + 1], p2 = pairs[i + 2], p3 = pairs[i + 3];
        float g0 = h2[(size_t)(p0.x & 0xFFFF) * OUT_DIM + d];
        float g1 = h2[(size_t)(p1.x & 0xFFFF) * OUT_DIM + d];
        float g2 = h2[(size_t)(p2.x & 0xFFFF) * OUT_DIM + d];
        float g3 = h2[(size_t)(p3.x & 0xFFFF) * OUT_DIM + d];
        acc += __int_as_float(p0.y) * g0 + __int_as_float(p1.y) * g1
             + __int_as_float(p2.y) * g2 + __int_as_float(p3.y) * g3;
    }
    for (; i < e; i++) {
        int2 pr = pairs[i];
        acc += __int_as_float(pr.y) * h2[(size_t)(pr.x & 0xFFFF) * OUT_DIM + d];
    }
    out[(size_t)n * OUT_DIM + d] = acc;
}

// ================= launch =================

extern "C" void kernel_launch(void* const* d_in, const int* in_sizes, int n_in,
                              void* d_out, int out_size, void* d_ws, size_t ws_size,
                              hipStream_t stream) {
    const float* feature   = (const float*)d_in[0];
    const int*   edge_src  = (const int*)d_in[1];
    const int*   edge_dst  = (const int*)d_in[2];
    const float* edge_vals = (const float*)d_in[3];
    const float* W1        = (const float*)d_in[4];
    const float* W2        = (const float*)d_in[5];
    float* out = (float*)d_out;

    char* ws = (char*)d_ws;
    size_t off = 0;
    auto alloc = [&](size_t bytes) {
        void* p = ws + off;
        off += (bytes + 255) & ~(size_t)255;
        return p;
    };
    unsigned short* h0    = (unsigned short*)alloc((size_t)N_NODES * HID_DIM * 2);
    unsigned short* Wt    = (unsigned short*)alloc((size_t)IN_DIM * HID_DIM * 2);
    float* h              = (float*)alloc((size_t)N_NODES * HID_DIM * 4);
    float* h2             = (float*)alloc((size_t)N_NODES * OUT_DIM * 4);
    int*   bcnt           = (int*)alloc((size_t)NB * 4);
    int*   bucket_ptr     = (int*)alloc((size_t)(NB + 1) * 4);
    int*   cursor         = (int*)alloc((size_t)NB * 4);
    int*   row_ptr        = (int*)alloc((size_t)(N_NODES + 1) * 4);
    int2*  pairs_bkt      = (int2*)alloc((size_t)N_EDGES * 8);
    int2*  pairs          = (int2*)alloc((size_t)N_EDGES * 8);

    hipMemsetAsync(bcnt, 0, (size_t)NB * 4, stream);

    bucket_hist_kernel<<<(N_EDGES + 4095) / 4096, 256, 0, stream>>>(edge_dst, bcnt);
    bucket_scan_kernel<<<1, 1024, 0, stream>>>(bcnt, bucket_ptr, cursor);
    bucket_scatter_kernel<<<(N_EDGES + 4095) / 4096, 256, 0, stream>>>(edge_src, edge_dst,
                                                                       edge_vals, cursor,
                                                                       pairs_bkt);
    node_sort_fused_kernel<<<NB, 256, 0, stream>>>(pairs_bkt, bucket_ptr, row_ptr, pairs);

    prep_w1_kernel<<<(IN_DIM * HID_DIM + 255) / 256, 256, 0, stream>>>(W1, Wt);
    gemm1_kernel<<<(N_NODES + 63) / 64, 256, 0, stream>>>(feature, Wt, h0);
    spmm1_node_kernel<<<(N_NODES + 3) / 4, 256, 0, stream>>>(h0, row_ptr, pairs, h);
    gemm2_kernel<<<(N_NODES + 15) / 16, 256, 0, stream>>>(h, W2, h2);
    spmm2_node_kernel<<<(N_NODES * 16 + 255) / 256, 256, 0, stream>>>(h2, row_ptr, pairs, out);
}

// Round 9
// 162.211 us; speedup vs baseline: 1.4877x; 1.1013x over previous
//
#include <hip/hip_runtime.h>

#define N_NODES 50000
#define N_EDGES 1600000
#define IN_DIM 512
#define HID_DIM 128
#define OUT_DIM 16

#define BKT_SHIFT 6
#define BKT_NODES 64
#define NB ((N_NODES + BKT_NODES - 1) / BKT_NODES)   // 782 buckets

typedef __attribute__((ext_vector_type(8))) __bf16 bf16x8;
typedef __attribute__((ext_vector_type(8))) unsigned short ushort8;
typedef __attribute__((ext_vector_type(4))) unsigned short ushort4v;
typedef __attribute__((ext_vector_type(4))) float f32x4;

static __device__ __forceinline__ unsigned short f2bf(float x) {
    unsigned int u = __float_as_uint(x);
    u += 0x7FFFu + ((u >> 16) & 1u);   // round-to-nearest-even
    return (unsigned short)(u >> 16);
}
static __device__ __forceinline__ float bf2f(unsigned short v) {
    return __uint_as_float(((unsigned int)v) << 16);
}

__device__ inline int wave_incl_scan(int v) {
    #pragma unroll
    for (int off = 1; off < 64; off <<= 1) {
        int x = __shfl_up(v, off, 64);
        if ((threadIdx.x & 63) >= off) v += x;
    }
    return v;
}

// ================= CSR build =================

__global__ void zero_bcnt_kernel(int* __restrict__ bcnt) {
    int t = threadIdx.x;
    if (t < NB) bcnt[t] = 0;
}

// 391 blocks x 1024 thr x 4096 edges
__global__ __launch_bounds__(1024) void bucket_hist_kernel(const int* __restrict__ dst,
                                                           int* __restrict__ bcnt) {
    __shared__ int lc[NB];
    const int t = threadIdx.x;
    for (int b = t; b < NB; b += 1024) lc[b] = 0;
    __syncthreads();
    const int e0 = blockIdx.x * 4096;
    #pragma unroll
    for (int i = 0; i < 4; i++) {
        int e = e0 + i * 1024 + t;
        if (e < N_EDGES) atomicAdd(&lc[dst[e] >> BKT_SHIFT], 1);
    }
    __syncthreads();
    for (int b = t; b < NB; b += 1024)
        if (lc[b]) atomicAdd(&bcnt[b], lc[b]);
}

__global__ __launch_bounds__(1024) void bucket_scan_kernel(const int* __restrict__ bcnt,
                                                           int* __restrict__ bucket_ptr,
                                                           int* __restrict__ cursor) {
    __shared__ int wsums[16];
    const int t = threadIdx.x;
    const int lane = t & 63, wid = t >> 6;
    int v = (t < NB) ? bcnt[t] : 0;
    int incl = wave_incl_scan(v);
    if (lane == 63) wsums[wid] = incl;
    __syncthreads();
    if (wid == 0) {
        int wv = (lane < 16) ? wsums[lane] : 0;
        int ws = wave_incl_scan(wv);
        if (lane < 16) wsums[lane] = ws;
    }
    __syncthreads();
    int woff = wid ? wsums[wid - 1] : 0;
    int excl = woff + incl - v;
    if (t < NB) { bucket_ptr[t] = excl; cursor[t] = excl; }
    if (t == NB - 1) bucket_ptr[NB] = excl + v;
}

// 391 blocks x 1024 thr x 4096 edges. pairs_bkt[i] = {src | (dstlocal<<16), val}
__global__ __launch_bounds__(1024) void bucket_scatter_kernel(const int* __restrict__ src,
                                                              const int* __restrict__ dst,
                                                              const float* __restrict__ val,
                                                              int* __restrict__ cursor,
                                                              int2* __restrict__ pairs_bkt) {
    __shared__ int cnt[NB];
    __shared__ int bbase[NB];
    const int t = threadIdx.x;
    const int e0 = blockIdx.x * 4096;
    for (int b = t; b < NB; b += 1024) cnt[b] = 0;
    __syncthreads();
    #pragma unroll
    for (int i = 0; i < 4; i++) {
        int e = e0 + i * 1024 + t;
        if (e < N_EDGES) atomicAdd(&cnt[dst[e] >> BKT_SHIFT], 1);
    }
    __syncthreads();
    for (int b = t; b < NB; b += 1024) {
        int c = cnt[b];
        bbase[b] = c ? atomicAdd(&cursor[b], c) : 0;
        cnt[b] = 0;
    }
    __syncthreads();
    #pragma unroll
    for (int i = 0; i < 4; i++) {
        int e = e0 + i * 1024 + t;
        if (e < N_EDGES) {
            int dd = dst[e];
            int b = dd >> BKT_SHIFT, dl = dd & (BKT_NODES - 1);
            int pos = bbase[b] + atomicAdd(&cnt[b], 1);
            int2 pr;
            pr.x = src[e] | (dl << 16);
            pr.y = __float_as_int(val[e]);
            pairs_bkt[pos] = pr;
        }
    }
}

// Fused node-level CSR: per bucket, hist by dst-local -> scan -> row_ptr -> permute.
__global__ __launch_bounds__(512) void node_sort_fused_kernel(const int2* __restrict__ pairs_bkt,
                                                              const int* __restrict__ bucket_ptr,
                                                              int* __restrict__ row_ptr,
                                                              int2* __restrict__ pairs) {
    __shared__ int cnt[BKT_NODES];
    __shared__ int base[BKT_NODES];
    const int t = threadIdx.x;
    const int b = blockIdx.x;
    const int s = bucket_ptr[b], e = bucket_ptr[b + 1];
    if (t < BKT_NODES) cnt[t] = 0;
    __syncthreads();
    for (int i = s + t; i < e; i += 512)
        atomicAdd(&cnt[pairs_bkt[i].x >> 16], 1);
    __syncthreads();
    if (t < BKT_NODES) {
        int v = cnt[t];
        int incl = wave_incl_scan(v);       // wave 0, lanes 0..63
        base[t] = s + incl - v;
    }
    __syncthreads();
    if (t < BKT_NODES) {
        int n = b * BKT_NODES + t;
        if (n < N_NODES) row_ptr[n] = base[t];
        cnt[t] = 0;
    }
    if (b == NB - 1 && t == 0) row_ptr[N_NODES] = N_EDGES;
    __syncthreads();
    for (int i = s + t; i < e; i += 512) {
        int2 pr = pairs_bkt[i];
        int dl = pr.x >> 16;
        int p = base[dl] + atomicAdd(&cnt[dl], 1);
        pairs[p] = pr;
    }
}

// ================= compute =================

__global__ void prep_w1_kernel(const float* __restrict__ W1, unsigned short* __restrict__ Wt) {
    int i = blockIdx.x * 256 + threadIdx.x;
    if (i < IN_DIM * HID_DIM) {
        int k = i >> 7, col = i & 127;
        Wt[(size_t)col * IN_DIM + k] = f2bf(W1[i]);
    }
}

// GEMM1 (bf16 MFMA, LDS-staged): h0 = bf16(X @ W1)
#define G1_XSTR 72
#define G1_BSTR 72
__global__ __launch_bounds__(256) void gemm1_kernel(const float* __restrict__ X,
                                                    const unsigned short* __restrict__ Wt,
                                                    unsigned short* __restrict__ h0) {
    __shared__ __align__(16) unsigned short Xs[64 * G1_XSTR];    // 9216 B
    __shared__ __align__(16) unsigned short Bs[128 * G1_BSTR];   // 18432 B
    const int t = threadIdx.x;
    const int lane = t & 63;
    const int wave = t >> 6;           // col group: cols wave*32 .. +31
    const int c = lane & 15, g = lane >> 4;
    const int m0 = blockIdx.x * 64;

    f32x4 acc[4][2];
    #pragma unroll
    for (int mt = 0; mt < 4; mt++)
        #pragma unroll
        for (int nt = 0; nt < 2; nt++) acc[mt][nt] = (f32x4){0.f, 0.f, 0.f, 0.f};

    float4 xr[4];
    ushort8 br[4];

    #define G1_LOAD(kt)                                                                  \
        _Pragma("unroll")                                                                \
        for (int p = 0; p < 4; p++) {                                                    \
            int idx = p * 256 + t;                                                       \
            int xrow = idx >> 4, xseg = idx & 15;                                        \
            int grow = m0 + xrow; grow = (grow < N_NODES) ? grow : (N_NODES - 1);        \
            xr[p] = *(const float4*)&X[(size_t)grow * IN_DIM + (kt) * 64 + xseg * 4];    \
            int bcol = idx >> 3, bseg = idx & 7;                                         \
            br[p] = *(const ushort8*)&Wt[(size_t)bcol * IN_DIM + (kt) * 64 + bseg * 8];  \
        }

    G1_LOAD(0)
    for (int kt = 0; kt < 8; kt++) {
        #pragma unroll
        for (int p = 0; p < 4; p++) {
            int idx = p * 256 + t;
            int xrow = idx >> 4, xseg = idx & 15;
            ushort4v xw;
            xw[0] = f2bf(xr[p].x); xw[1] = f2bf(xr[p].y);
            xw[2] = f2bf(xr[p].z); xw[3] = f2bf(xr[p].w);
            *(ushort4v*)&Xs[xrow * G1_XSTR + xseg * 4] = xw;
            int bcol = idx >> 3, bseg = idx & 7;
            *(ushort8*)&Bs[bcol * G1_BSTR + bseg * 8] = br[p];
        }
        __syncthreads();
        if (kt < 7) G1_LOAD(kt + 1)        // prefetch next tile (hidden under MFMA)
        #pragma unroll
        for (int ks = 0; ks < 2; ks++) {
            bf16x8 bf[2];
            #pragma unroll
            for (int nt = 0; nt < 2; nt++) {
                int col = wave * 32 + nt * 16 + c;
                bf[nt] = *(const bf16x8*)&Bs[col * G1_BSTR + ks * 32 + g * 8];
            }
            #pragma unroll
            for (int mt = 0; mt < 4; mt++) {
                bf16x8 af = *(const bf16x8*)&Xs[(mt * 16 + c) * G1_XSTR + ks * 32 + g * 8];
                #pragma unroll
                for (int nt = 0; nt < 2; nt++)
                    acc[mt][nt] = __builtin_amdgcn_mfma_f32_16x16x32_bf16(af, bf[nt],
                                                                          acc[mt][nt], 0, 0, 0);
            }
        }
        __syncthreads();
    }
    #undef G1_LOAD

    #pragma unroll
    for (int mt = 0; mt < 4; mt++) {
        #pragma unroll
        for (int r = 0; r < 4; r++) {
            int row = m0 + mt * 16 + g * 4 + r;
            if (row < N_NODES) {
                #pragma unroll
                for (int nt = 0; nt < 2; nt++) {
                    int col = wave * 32 + nt * 16 + c;
                    h0[(size_t)row * HID_DIM + col] = f2bf(acc[mt][nt][r]);
                }
            }
        }
    }
}

// SpMM1 + ReLU: one wave per dst node; batch-8 clamped (no serial tail); h out bf16.
__global__ __launch_bounds__(256) void spmm1_node_kernel(const unsigned short* __restrict__ h0,
                                                         const int* __restrict__ row_ptr,
                                                         const int2* __restrict__ pairs,
                                                         unsigned short* __restrict__ h) {
    const int wid = __builtin_amdgcn_readfirstlane(threadIdx.x >> 6);
    const int n = blockIdx.x * 4 + wid;            // wave-uniform, max 49999
    const int lane = threadIdx.x & 63;
    const int s = row_ptr[n], e = row_ptr[n + 1];  // scalar loads
    const unsigned short* h0l = h0 + lane * 2;
    float ax = 0.f, ay = 0.f;
    for (int base = s; base < e; base += 8) {
        float vv[8];
        const unsigned short* rp[8];
        #pragma unroll
        for (int k = 0; k < 8; k++) {
            int idx = base + k;
            int cidx = (idx < e) ? idx : (e - 1);     // scalar select; e-1 >= s valid
            int2 pr = pairs[cidx];
            vv[k] = (idx < e) ? __int_as_float(pr.y) : 0.f;
            rp[k] = h0l + (size_t)(pr.x & 0xFFFF) * HID_DIM;
        }
        unsigned int gg[8];
        #pragma unroll
        for (int k = 0; k < 8; k++) gg[k] = *(const unsigned int*)rp[k];
        #pragma unroll
        for (int k = 0; k < 8; k++) {
            ax += vv[k] * bf2f((unsigned short)gg[k]);
            ay += vv[k] * bf2f((unsigned short)(gg[k] >> 16));
        }
    }
    unsigned int w = ((unsigned int)f2bf(fmaxf(ay, 0.f)) << 16) | f2bf(fmaxf(ax, 0.f));
    ((unsigned int*)(h + (size_t)n * HID_DIM))[lane] = w;
}

// GEMM2: h2[N,16] = h[N,128](bf16) @ W2[128,16]
__global__ __launch_bounds__(256) void gemm2_kernel(const unsigned short* __restrict__ H,
                                                    const float* __restrict__ W2,
                                                    float* __restrict__ C) {
    __shared__ float Hs[16][132];
    __shared__ float Ws[128][16];
    const int t = threadIdx.x;
    const int n0 = blockIdx.x * 16;
    #pragma unroll
    for (int p = 0; p < 2; p++) {
        int idx = p * 256 + t;
        ((float4*)Ws)[idx] = ((const float4*)W2)[idx];
    }
    {   // H tile: 16 rows x 128 bf16, one ushort8 per thread
        int row = t >> 4, seg = t & 15;
        int gr = n0 + row;
        ushort8 hv = {0, 0, 0, 0, 0, 0, 0, 0};
        if (gr < N_NODES) hv = *(const ushort8*)&H[(size_t)gr * HID_DIM + seg * 8];
        #pragma unroll
        for (int j = 0; j < 8; j++) Hs[row][seg * 8 + j] = bf2f(hv[j]);
    }
    __syncthreads();
    const int nl = t >> 4, j = t & 15;
    float acc = 0.f;
    #pragma unroll 8
    for (int k = 0; k < 128; k++) acc += Hs[nl][k] * Ws[k][j];
    int n = n0 + nl;
    if (n < N_NODES) C[(size_t)n * OUT_DIM + j] = acc;
}

// SpMM2: quarter-wave (16 lanes) per dst node.
__global__ __launch_bounds__(256) void spmm2_node_kernel(const float* __restrict__ h2,
                                                         const int* __restrict__ row_ptr,
                                                         const int2* __restrict__ pairs,
                                                         float* __restrict__ out) {
    const int idx = blockIdx.x * 256 + threadIdx.x;
    const int n = idx >> 4;
    const int d = idx & 15;
    if (n >= N_NODES) return;
    const int s = row_ptr[n], e = row_ptr[n + 1];
    float acc = 0.f;
    int i = s;
    for (; i + 4 <= e; i += 4) {
        int2 p0 = pairs[i], p1 = pairs[i + 1], p2 = pairs[i + 2], p3 = pairs[i + 3];
        float g0 = h2[(size_t)(p0.x & 0xFFFF) * OUT_DIM + d];
        float g1 = h2[(size_t)(p1.x & 0xFFFF) * OUT_DIM + d];
        float g2 = h2[(size_t)(p2.x & 0xFFFF) * OUT_DIM + d];
        float g3 = h2[(size_t)(p3.x & 0xFFFF) * OUT_DIM + d];
        acc += __int_as_float(p0.y) * g0 + __int_as_float(p1.y) * g1
             + __int_as_float(p2.y) * g2 + __int_as_float(p3.y) * g3;
    }
    for (; i < e; i++) {
        int2 pr = pairs[i];
        acc += __int_as_float(pr.y) * h2[(size_t)(pr.x & 0xFFFF) * OUT_DIM + d];
    }
    out[(size_t)n * OUT_DIM + d] = acc;
}

// ================= launch =================

extern "C" void kernel_launch(void* const* d_in, const int* in_sizes, int n_in,
                              void* d_out, int out_size, void* d_ws, size_t ws_size,
                              hipStream_t stream) {
    const float* feature   = (const float*)d_in[0];
    const int*   edge_src  = (const int*)d_in[1];
    const int*   edge_dst  = (const int*)d_in[2];
    const float* edge_vals = (const float*)d_in[3];
    const float* W1        = (const float*)d_in[4];
    const float* W2        = (const float*)d_in[5];
    float* out = (float*)d_out;

    char* ws = (char*)d_ws;
    size_t off = 0;
    auto alloc = [&](size_t bytes) {
        void* p = ws + off;
        off += (bytes + 255) & ~(size_t)255;
        return p;
    };
    unsigned short* h0    = (unsigned short*)alloc((size_t)N_NODES * HID_DIM * 2);
    unsigned short* Wt    = (unsigned short*)alloc((size_t)IN_DIM * HID_DIM * 2);
    unsigned short* h     = (unsigned short*)alloc((size_t)N_NODES * HID_DIM * 2);
    float* h2             = (float*)alloc((size_t)N_NODES * OUT_DIM * 4);
    int*   bcnt           = (int*)alloc((size_t)NB * 4);
    int*   bucket_ptr     = (int*)alloc((size_t)(NB + 1) * 4);
    int*   cursor         = (int*)alloc((size_t)NB * 4);
    int*   row_ptr        = (int*)alloc((size_t)(N_NODES + 1) * 4);
    int2*  pairs_bkt      = (int2*)alloc((size_t)N_EDGES * 8);
    int2*  pairs          = (int2*)alloc((size_t)N_EDGES * 8);

    zero_bcnt_kernel<<<1, 1024, 0, stream>>>(bcnt);
    bucket_hist_kernel<<<(N_EDGES + 4095) / 4096, 1024, 0, stream>>>(edge_dst, bcnt);
    bucket_scan_kernel<<<1, 1024, 0, stream>>>(bcnt, bucket_ptr, cursor);
    bucket_scatter_kernel<<<(N_EDGES + 4095) / 4096, 1024, 0, stream>>>(edge_src, edge_dst,
                                                                        edge_vals, cursor,
                                                                        pairs_bkt);
    node_sort_fused_kernel<<<NB, 512, 0, stream>>>(pairs_bkt, bucket_ptr, row_ptr, pairs);

    prep_w1_kernel<<<(IN_DIM * HID_DIM + 255) / 256, 256, 0, stream>>>(W1, Wt);
    gemm1_kernel<<<(N_NODES + 63) / 64, 256, 0, stream>>>(feature, Wt, h0);
    spmm1_node_kernel<<<(N_NODES + 3) / 4, 256, 0, stream>>>(h0, row_ptr, pairs, h);
    gemm2_kernel<<<(N_NODES + 15) / 16, 256, 0, stream>>>(h, W2, h2);
    spmm2_node_kernel<<<(N_NODES * 16 + 255) / 256, 256, 0, stream>>>(h2, row_ptr, pairs, out);
}